// Round 1
// baseline (193.581 us; speedup 1.0000x reference)
//
#include <hip/hip_runtime.h>

// RX(theta) on `qubit` of a [B, 2^nq] complex state (real/imag split, fp32).
//   nr0 = c*r0 + s*i1 ; ni0 = c*i0 - s*r1
//   nr1 = c*r1 + s*i0 ; ni1 = c*i1 - s*r0
// where c = cos(theta/2), s = sin(theta/2), pair stride = right = 2^(nq-q-1).
//
// Memory-bound: each element read once, written once. 4 pairs/thread via
// float4 (right = 2^18 >> 4, so 4 consecutive pairs are contiguous & aligned).

__global__ void rx_gate_kernel(const float* __restrict__ sr,
                               const float* __restrict__ si,
                               const float* __restrict__ theta,
                               const int* __restrict__ qubit_p,
                               const int* __restrict__ nq_p,
                               float* __restrict__ out_r,
                               float* __restrict__ out_i,
                               long long npairs) {
    long long t = (long long)blockIdx.x * blockDim.x + threadIdx.x;
    long long p = t * 4;  // first pair index handled by this thread
    if (p >= npairs) return;

    const int shift = nq_p[0] - qubit_p[0] - 1;   // log2(right)
    const long long right = 1ll << shift;
    const long long mask = right - 1;

    const float half = 0.5f * theta[0];
    const float c = cosf(half);
    const float s = sinf(half);

    if (((right & 3) == 0) && (p + 4 <= npairs)) {
        // vector path: 4 consecutive pairs, contiguous, 16B-aligned
        const long long idx0 = ((p >> shift) << (shift + 1)) | (p & mask);
        const float4 R0 = *(const float4*)(sr + idx0);
        const float4 R1 = *(const float4*)(sr + idx0 + right);
        const float4 I0 = *(const float4*)(si + idx0);
        const float4 I1 = *(const float4*)(si + idx0 + right);
        float4 NR0, NR1, NI0, NI1;
        const float* r0 = (const float*)&R0;
        const float* r1 = (const float*)&R1;
        const float* i0 = (const float*)&I0;
        const float* i1 = (const float*)&I1;
        float* nr0 = (float*)&NR0;
        float* nr1 = (float*)&NR1;
        float* ni0 = (float*)&NI0;
        float* ni1 = (float*)&NI1;
#pragma unroll
        for (int k = 0; k < 4; ++k) {
            nr0[k] = fmaf(c, r0[k],  s * i1[k]);
            ni0[k] = fmaf(c, i0[k], -s * r1[k]);
            nr1[k] = fmaf(c, r1[k],  s * i0[k]);
            ni1[k] = fmaf(c, i1[k], -s * r0[k]);
        }
        *(float4*)(out_r + idx0)         = NR0;
        *(float4*)(out_r + idx0 + right) = NR1;
        *(float4*)(out_i + idx0)         = NI0;
        *(float4*)(out_i + idx0 + right) = NI1;
    } else {
        // scalar fallback (tail, or right < 4)
        for (int k = 0; k < 4; ++k) {
            const long long pk = p + k;
            if (pk >= npairs) break;
            const long long idx = ((pk >> shift) << (shift + 1)) | (pk & mask);
            const float r0 = sr[idx];
            const float r1 = sr[idx + right];
            const float i0 = si[idx];
            const float i1 = si[idx + right];
            out_r[idx]         = fmaf(c, r0,  s * i1);
            out_i[idx]         = fmaf(c, i0, -s * r1);
            out_r[idx + right] = fmaf(c, r1,  s * i0);
            out_i[idx + right] = fmaf(c, i1, -s * r0);
        }
    }
}

extern "C" void kernel_launch(void* const* d_in, const int* in_sizes, int n_in,
                              void* d_out, int out_size, void* d_ws, size_t ws_size,
                              hipStream_t stream) {
    const float* sr    = (const float*)d_in[0];
    const float* si    = (const float*)d_in[1];
    const float* theta = (const float*)d_in[2];
    const int* qubit_p = (const int*)d_in[3];
    const int* nq_p    = (const int*)d_in[4];

    const long long n = (long long)in_sizes[0];   // B * 2^nq elements per array
    float* out_r = (float*)d_out;
    float* out_i = out_r + n;

    const long long npairs   = n / 2;
    const long long nthreads = (npairs + 3) / 4;
    const int block = 256;
    const long long grid = (nthreads + block - 1) / block;

    rx_gate_kernel<<<dim3((unsigned)grid), dim3(block), 0, stream>>>(
        sr, si, theta, qubit_p, nq_p, out_r, out_i, npairs);
}